// Round 16
// baseline (166.855 us; speedup 1.0000x reference)
//
#include <hip/hip_runtime.h>
#include <math.h>

#define NSAMP 8
#define CH 64
#define HH 64
#define WW 64
#define SPATIAL 4096        // HH*WW
#define PER_SAMPLE 262144   // CH*SPATIAL
#define NTOK 32768          // NSAMP*SPATIAL
#define NHEADS 4
#define HD 16
#define KS 7
#define EPS 1e-5f
#define QSCALE 0.25f        // HD^-0.5

typedef __attribute__((ext_vector_type(8))) short short8;
typedef __attribute__((ext_vector_type(4))) float f32x4;
typedef _Float16 hf2 __attribute__((ext_vector_type(2)));

__device__ __forceinline__ unsigned short f2bf(float f) {
    unsigned u = __float_as_uint(f);
    u = u + 0x7fffu + ((u >> 16) & 1u);     // round-to-nearest-even
    return (unsigned short)(u >> 16);
}
__device__ __forceinline__ unsigned pack2(float a, float b) {
    return (unsigned)f2bf(a) | ((unsigned)f2bf(b) << 16);
}
// fp16 helpers (q/k/v tensors are fp16: enables v_fma_mix_f32 consumption)
__device__ __forceinline__ unsigned short f2h(float f) {
    _Float16 h = (_Float16)f;               // v_cvt_f16_f32 (RNE)
    return __builtin_bit_cast(unsigned short, h);
}
__device__ __forceinline__ unsigned pack2h(float a, float b) {
    return (unsigned)f2h(a) | ((unsigned)f2h(b) << 16);
}
__device__ __forceinline__ hf2 u2h(unsigned u) { return __builtin_bit_cast(hf2, u); }

// 4-elem fp16 dot: 4x v_fma_mix_f32
__device__ __forceinline__ float dot4_h(uint2 k, uint2 q) {
    hf2 a0 = u2h(k.x), a1 = u2h(k.y);
    hf2 b0 = u2h(q.x), b1 = u2h(q.y);
    float s;
    s = (float)a0.x * (float)b0.x;
    s = fmaf((float)a0.y, (float)b0.y, s);
    s = fmaf((float)a1.x, (float)b1.x, s);
    s = fmaf((float)a1.y, (float)b1.y, s);
    return s;
}
__device__ __forceinline__ void pv4_h(uint2 v, float p, float* acc) {
    hf2 a0 = u2h(v.x), a1 = u2h(v.y);
    acc[0] = fmaf(p, (float)a0.x, acc[0]);
    acc[1] = fmaf(p, (float)a0.y, acc[1]);
    acc[2] = fmaf(p, (float)a1.x, acc[2]);
    acc[3] = fmaf(p, (float)a1.y, acc[3]);
}

// ---------------- K1: per-sample partial sum/sumsq (blocks 0-255, NO atomics) ----------------
//                  + weight->bf16 (blocks 256-447)
__global__ __launch_bounds__(256) void k_statsprep(const float* __restrict__ x,
                                                   float* __restrict__ stats,
                                                   const float* __restrict__ qkv_w,
                                                   const float* __restrict__ fc1_w,
                                                   const float* __restrict__ fc2_w,
                                                   const float* __restrict__ proj_w,
                                                   unsigned short* __restrict__ wb) {
    int blk = blockIdx.x;
    if (blk >= 256) {           // prep: 192 blocks x 256 = 49152 weights
        int i = (blk - 256) * 256 + threadIdx.x;
        if (i < 12288)      wb[i] = f2bf(qkv_w[i]);
        else if (i < 28672) wb[i] = f2bf(fc1_w[i - 12288]);
        else if (i < 45056) wb[i] = f2bf(fc2_w[i - 28672]);
        else                wb[i] = f2bf(proj_w[i - 45056]);
        return;
    }
    int n = blk >> 5, chunk = blk & 31;
    const float4* p4 = (const float4*)(x + n * PER_SAMPLE + chunk * 8192);
    int t = threadIdx.x;
    float s1 = 0.f, s2 = 0.f;
#pragma unroll
    for (int i = 0; i < 8; i++) {
        float4 v = p4[t + i * 256];
        s1 += v.x + v.y + v.z + v.w;
        s2 += v.x * v.x + v.y * v.y + v.z * v.z + v.w * v.w;
    }
#pragma unroll
    for (int off = 1; off < 64; off <<= 1) {
        s1 += __shfl_xor(s1, off);
        s2 += __shfl_xor(s2, off);
    }
    __shared__ float r1[4], r2[4];
    int lane = t & 63, wv = t >> 6;
    if (lane == 0) { r1[wv] = s1; r2[wv] = s2; }
    __syncthreads();
    if (t == 0) {
        stats[(n * 32 + chunk) * 2 + 0] = r1[0] + r1[1] + r1[2] + r1[3];
        stats[(n * 32 + chunk) * 2 + 1] = r2[0] + r2[1] + r2[2] + r2[3];
    }
}

// ---------------- K2: GN + QKV GEMM via MFMA -> fp16 q / kv ----------------
__global__ __launch_bounds__(256) void k_qkv(const float* __restrict__ x,
                                             const float* __restrict__ stats,
                                             const float* __restrict__ gn_w,
                                             const float* __restrict__ gn_b,
                                             const unsigned short* __restrict__ qkv_wb,
                                             const float* __restrict__ qkv_b,
                                             uint4* __restrict__ qb8,
                                             uint4* __restrict__ kvb8) {
    __shared__ __attribute__((aligned(16))) short xA[4 * 2 * 64 * 8];  // 8 KB frag-major A
    __shared__ float obuf[4][16 * 65];                                 // per-wave transpose
    int s0 = blockIdx.x * 64;
    int smp = s0 >> 12, sp = s0 & 4095;
    int t = threadIdx.x, tok = t & 63, g = t >> 6;

    // sum the 32 per-chunk partials for this sample (uniform across block)
    float ps1 = 0.f, ps2 = 0.f;
    {
        const float2* pp = (const float2*)stats + smp * 32;
#pragma unroll
        for (int i = 0; i < 32; i++) {
            float2 p = pp[i];
            ps1 += p.x;
            ps2 += p.y;
        }
    }
    float mu = ps1 * (1.f / (float)PER_SAMPLE);
    float var = ps2 * (1.f / (float)PER_SAMPLE) - mu * mu;
    float rstd = rsqrtf(var + EPS);

    {
        const float* xp = x + smp * PER_SAMPLE + sp + tok;
        float v[16];
#pragma unroll
        for (int i = 0; i < 16; i++) {
            int c = g * 16 + i;
            v[i] = (xp[(size_t)c * SPATIAL] - mu) * rstd * gn_w[c] + gn_b[c];
        }
#pragma unroll
        for (int e = 0; e < 2; e++) {
            int cb = 2 * g + e;
            int kf = cb >> 2, qq = cb & 3;
            uint4 p;
            p.x = pack2(v[e * 8 + 0], v[e * 8 + 1]);
            p.y = pack2(v[e * 8 + 2], v[e * 8 + 3]);
            p.z = pack2(v[e * 8 + 4], v[e * 8 + 5]);
            p.w = pack2(v[e * 8 + 6], v[e * 8 + 7]);
            int chunk = ((tok >> 4) * 2 + kf) * 64 + (tok & 15) + (qq << 4);
            *(uint4*)&xA[chunk * 8] = p;
        }
    }
    __syncthreads();

    int w = __builtin_amdgcn_readfirstlane(g);
    int lane = t & 63, nh = lane & 15, qd = lane >> 4;

    short8 af[8];
#pragma unroll
    for (int mt = 0; mt < 4; mt++)
#pragma unroll
        for (int kf = 0; kf < 2; kf++)
            af[mt * 2 + kf] = *(const short8*)&xA[((mt * 2 + kf) * 64 + lane) * 8];

    for (int nt = 0; nt < 3; nt++) {
        int n0 = w * 48 + nt * 16;
        const unsigned short* wp = qkv_wb + (size_t)(n0 + nh) * 64 + qd * 8;
        short8 b0 = *(const short8*)(wp);
        short8 b1 = *(const short8*)(wp + 32);
        float bias = qkv_b[n0 + nh];
        bool isq = (n0 < 64);
        f32x4 acc[4];
#pragma unroll
        for (int mt = 0; mt < 4; mt++) {
            f32x4 d = {0.f, 0.f, 0.f, 0.f};
            d = __builtin_amdgcn_mfma_f32_16x16x32_bf16(af[mt * 2 + 0], b0, d, 0, 0, 0);
            d = __builtin_amdgcn_mfma_f32_16x16x32_bf16(af[mt * 2 + 1], b1, d, 0, 0, 0);
            acc[mt] = d;
        }
#pragma unroll
        for (int mt = 0; mt < 4; mt++)
#pragma unroll
            for (int r = 0; r < 4; r++) {
                float vv = acc[mt][r] + bias;
                if (isq) vv *= QSCALE;
                obuf[w][nh * 65 + mt * 16 + qd * 4 + r] = vv;
            }
        __builtin_amdgcn_wave_barrier();     // obuf is per-wave; DS in-order per wave
#pragma unroll
        for (int u = 0; u < 2; u++) {
            uint4 p;
            p.x = pack2h(obuf[w][(u * 8 + 0) * 65 + lane], obuf[w][(u * 8 + 1) * 65 + lane]);
            p.y = pack2h(obuf[w][(u * 8 + 2) * 65 + lane], obuf[w][(u * 8 + 3) * 65 + lane]);
            p.z = pack2h(obuf[w][(u * 8 + 4) * 65 + lane], obuf[w][(u * 8 + 5) * 65 + lane]);
            p.w = pack2h(obuf[w][(u * 8 + 6) * 65 + lane], obuf[w][(u * 8 + 7) * 65 + lane]);
            if (n0 < 64)
                qb8[(size_t)((n0 >> 3) + u) * NTOK + s0 + lane] = p;
            else if (n0 < 128)
                kvb8[(size_t)(((n0 - 64) >> 3) + u) * NTOK + s0 + lane] = p;
            else
                kvb8[(size_t)(8 + ((n0 - 128) >> 3) + u) * NTOK + s0 + lane] = p;
        }
        __builtin_amdgcn_wave_barrier();     // before next nt rewrites obuf[w]
    }
}

// ---------------- K3: attention + proj + LN + MLP, fused; block = 32 tokens (half-row) ----------------
// NOW 512 threads (8 waves) per block, 1024 blocks -> 8192 waves = 32/CU (100% occupancy
// target, vs 16/CU before — the grid itself was capping latency hiding at 4 waves/SIMD).
// Lane granularity halved: wave g2=(head g, token-half th); lane = token16(w2t) x quarter(q).
// Each lane: 4 channels (uint2 K/V loads, dot4 + two intra-wave shfl_xor(16/32) combine,
// pv4, acc[4]). MFMA phases: wave (g,th) computes the mt=th half of each M=32 tile.
// Per-thread state ~halves -> fits the 64-VGPR cap of __launch_bounds__(512,8).
__global__ __launch_bounds__(512, 8) void k_fused(const uint4* __restrict__ qb8,
                                               const uint4* __restrict__ kvb8,
                                               const float* __restrict__ rpb,
                                               const unsigned short* __restrict__ proj_wb,
                                               const float* __restrict__ proj_b,
                                               const float* __restrict__ x,
                                               const float* __restrict__ ln_w,
                                               const float* __restrict__ ln_b,
                                               const unsigned short* __restrict__ fc1_wb,
                                               const float* __restrict__ fc1_b,
                                               const unsigned short* __restrict__ fc2_wb,
                                               const float* __restrict__ fc2_b,
                                               float* __restrict__ out) {
    __shared__ __attribute__((aligned(16))) short fragA[2 * 2 * 64 * 8];  // 4 KB (attn-out, then yn)
    __shared__ __attribute__((aligned(16))) short lhA[2 * 8 * 64 * 8];    // 16 KB (full hidden, M=32)
    __shared__ float obuf[8][16 * 17];                                    // 8.5 KB per-wave transpose (M=16)
    __shared__ float red1[512], red2[512];                                // 4 KB
    // XCD swizzle: same-XCD blocks cover 8-row chunks; half-row pairs adjacent.
    int xcd = blockIdx.x & 7, idx = blockIdx.x >> 3;
    int half = idx & 1;
    int h = xcd * 8 + ((idx >> 1) & 7);
    int n = idx >> 4;
    int t = threadIdx.x, lane = t & 63;
    int g2 = __builtin_amdgcn_readfirstlane(t >> 6);  // wave 0..7
    int g = g2 >> 1;               // head
    int th = g2 & 1;               // token-half (16-token group within the 32-token half-row)
    int w2t = lane & 15;           // token within group
    int q = lane >> 4;             // channel quarter (4 channels) within head
    int w2 = th * 16 + w2t;        // token within half-row
    int w = half * 32 + w2;        // actual column
    int rowbase = n * 4096 + h * 64;
    int cb = 2 * g + (q >> 1);     // 8-channel block id
    int qsub = q & 1;              // which uint2 half of the 8-channel block

    // ---- neighborhood attention, one-pass streaming softmax ----
    uint2 qa = ((const uint2*)qb8)[((size_t)cb * NTOK + rowbase + w) * 2 + qsub];
    int sh = min(max(h - 3, 0), HH - KS);
    int sw = min(max(w - 3, 0), WW - KS);
    const uint2* kp2 = (const uint2*)(kvb8 + (size_t)cb * NTOK);
    const uint2* vp2 = (const uint2*)(kvb8 + (size_t)(8 + cb) * NTOK);

    float sum = 0.f;
    float acc[4];
#pragma unroll
    for (int i = 0; i < 4; i++) acc[i] = 0.f;

#pragma unroll
    for (int a = 0; a < 7; a++) {
        int nb = n * 4096 + (sh + a) * 64 + sw;
        const float* rp = rpb + (g * 13 + (h - sh + 6 - a)) * 13 + (w - sw + 6);
#pragma unroll
        for (int bb = 0; bb < 7; bb++) {
            uint2 kv = kp2[(size_t)(nb + bb) * 2 + qsub];
            uint2 vv = vp2[(size_t)(nb + bb) * 2 + qsub];
            float dq = dot4_h(kv, qa);
            float d = dq + __shfl_xor(dq, 16);     // combine quarter pairs
            d += __shfl_xor(d, 32);                // combine halves -> full 16-dot
            d += rp[-bb];
            float e = __expf(d);
            sum += e;
            pv4_h(vv, e, acc);
        }
    }
    float rs = 1.f / sum;

    // x residual loads AFTER the fat loop (4 channels per lane)
    const float* xr = x + n * PER_SAMPLE + h * 64 + w;
    float xres[4];
#pragma unroll
    for (int i = 0; i < 4; i++)
        xres[i] = xr[(size_t)(g * 16 + q * 4 + i) * SPATIAL];

    // stage attn-out (x rs) as bf16 A-frags (M=32, K=64): m=w2, k = g*16+q*4+i
    int kf = cb >> 2, qsel = cb & 3;
    int chunk = ((w2 >> 4) * 2 + kf) * 64 + (w2 & 15) + (qsel << 4);
    {
        uint2 p2;
        p2.x = pack2(acc[0] * rs, acc[1] * rs);
        p2.y = pack2(acc[2] * rs, acc[3] * rs);
        *(uint2*)&fragA[chunk * 8 + qsub * 4] = p2;
    }
    __syncthreads();                                    // B1

    int nh = lane & 15, qd = lane >> 4;
    float yreg[4];                     // y = proj(attn)+bias+x, channels g*16+q*4+i, token w2
    // ---- proj MFMA: wave (g,th) computes M-tile mt=th, N=16 (channels g*16+nh) ----
    {
        short8 af0 = *(const short8*)&fragA[((th * 2 + 0) * 64 + lane) * 8];
        short8 af1 = *(const short8*)&fragA[((th * 2 + 1) * 64 + lane) * 8];
        int n0 = g * 16;
        const unsigned short* wp = proj_wb + (size_t)(n0 + nh) * 64 + qd * 8;
        short8 b0 = *(const short8*)(wp);
        short8 b1 = *(const short8*)(wp + 32);
        float bias = proj_b[n0 + nh];
        f32x4 d = {0.f, 0.f, 0.f, 0.f};
        d = __builtin_amdgcn_mfma_f32_16x16x32_bf16(af0, b0, d, 0, 0, 0);
        d = __builtin_amdgcn_mfma_f32_16x16x32_bf16(af1, b1, d, 0, 0, 0);
#pragma unroll
        for (int r = 0; r < 4; r++)
            obuf[g2][nh * 17 + qd * 4 + r] = d[r] + bias;
        __builtin_amdgcn_wave_barrier();   // obuf is per-wave; DS in-order per wave
#pragma unroll
        for (int i = 0; i < 4; i++)
            yreg[i] = obuf[g2][(q * 4 + i) * 17 + w2t] + xres[i];
    }

    // ---- LN (16 threads per token) -> fragA (yn A-frags) ----
    {
        float s1 = 0.f, s2 = 0.f;
#pragma unroll
        for (int i = 0; i < 4; i++) { s1 += yreg[i]; s2 += yreg[i] * yreg[i]; }
        red1[t] = s1;
        red2[t] = s2;
        __syncthreads();                                // B2 (also orders fragA reuse)
        float m1 = 0.f, m2 = 0.f;
#pragma unroll
        for (int gg = 0; gg < 4; gg++)
#pragma unroll
            for (int qq = 0; qq < 4; qq++) {
                int tt = (gg * 2 + th) * 64 + qq * 16 + w2t;
                m1 += red1[tt];
                m2 += red2[tt];
            }
        float mu = m1 * (1.f / 64.f);
        float rstd = rsqrtf(m2 * (1.f / 64.f) - mu * mu + EPS);
        float v[4];
#pragma unroll
        for (int i = 0; i < 4; i++) {
            int c = g * 16 + q * 4 + i;
            v[i] = (yreg[i] - mu) * rstd * ln_w[c] + ln_b[c];
        }
        uint2 p2;
        p2.x = pack2(v[0], v[1]);
        p2.y = pack2(v[2], v[3]);
        *(uint2*)&fragA[chunk * 8 + qsub * 4] = p2;
    }
    __syncthreads();                                    // B3

    // ---- fc1 + GELU -> lhA (fc2 A-frag layout, M=32, K=256); wave (g,th): mt=th ----
    {
        short8 yf0 = *(const short8*)&fragA[((th * 2 + 0) * 64 + lane) * 8];
        short8 yf1 = *(const short8*)&fragA[((th * 2 + 1) * 64 + lane) * 8];
#pragma unroll
        for (int nt = 0; nt < 4; nt++) {
            int n0f = g * 64 + nt * 16;
            const unsigned short* wp = fc1_wb + (size_t)(n0f + nh) * 64 + qd * 8;
            short8 b0 = *(const short8*)(wp);
            short8 b1 = *(const short8*)(wp + 32);
            float bias = fc1_b[n0f + nh];
            int j = n0f + nh;
            int kfA = j >> 5, q2j = (j >> 3) & 3, jb = j & 7;
            f32x4 d = {0.f, 0.f, 0.f, 0.f};
            d = __builtin_amdgcn_mfma_f32_16x16x32_bf16(yf0, b0, d, 0, 0, 0);
            d = __builtin_amdgcn_mfma_f32_16x16x32_bf16(yf1, b1, d, 0, 0, 0);
#pragma unroll
            for (int r = 0; r < 4; r++) {
                float hv = d[r] + bias;
                // tanh-form GELU via sigmoid: x*sigma(1.5958(x+0.044715x^3))
                float t2 = -1.5957691216f * fmaf(0.044715f * hv * hv, hv, hv);
                hv = hv / (1.f + __expf(t2));
                lhA[((th * 8 + kfA) * 64 + (qd * 4 + r) + (q2j << 4)) * 8 + jb] = (short)f2bf(hv);
            }
        }
    }
    __syncthreads();                                    // B4

    // ---- fc2 (wave (g,th): N=16 channels g*16+nh, mt=th, K=256) ----
    f32x4 acc2 = {0.f, 0.f, 0.f, 0.f};
#pragma unroll
    for (int kfA = 0; kfA < 8; kfA++) {
        const unsigned short* wp = fc2_wb + (size_t)(g * 16 + nh) * 256 + kfA * 32 + qd * 8;
        short8 bw = *(const short8*)(wp);
        short8 a = *(const short8*)&lhA[((th * 8 + kfA) * 64 + lane) * 8];
        acc2 = __builtin_amdgcn_mfma_f32_16x16x32_bf16(a, bw, acc2, 0, 0, 0);
    }
    // ---- epilogue: per-wave transpose, + fc2_b + y residual, NCHW store ----
#pragma unroll
    for (int r = 0; r < 4; r++)
        obuf[g2][nh * 17 + qd * 4 + r] = acc2[r];
    __builtin_amdgcn_wave_barrier();
    float* op = out + (size_t)n * PER_SAMPLE + h * 64 + w;
#pragma unroll
    for (int i = 0; i < 4; i++) {
        int c = g * 16 + q * 4 + i;
        op[(size_t)c * SPATIAL] = obuf[g2][(q * 4 + i) * 17 + w2t] + fc2_b[c] + yreg[i];
    }
}

extern "C" void kernel_launch(void* const* d_in, const int* in_sizes, int n_in,
                              void* d_out, int out_size, void* d_ws, size_t ws_size,
                              hipStream_t stream) {
    const float* x      = (const float*)d_in[0];
    const float* gn_w   = (const float*)d_in[1];
    const float* gn_b   = (const float*)d_in[2];
    const float* qkv_w  = (const float*)d_in[3];
    const float* qkv_b  = (const float*)d_in[4];
    const float* rpb    = (const float*)d_in[5];
    const float* proj_w = (const float*)d_in[6];
    const float* proj_b = (const float*)d_in[7];
    const float* ln_w   = (const float*)d_in[8];
    const float* ln_b   = (const float*)d_in[9];
    const float* fc1_w  = (const float*)d_in[10];
    const float* fc1_b  = (const float*)d_in[11];
    const float* fc2_w  = (const float*)d_in[12];
    const float* fc2_b  = (const float*)d_in[13];
    float* out = (float*)d_out;

    float* ws    = (float*)d_ws;
    float* stats = ws;                                      // 256 float2 partials = 2 KB
    uint4* qb8   = (uint4*)(ws + 512);                      // 8  * NTOK uint4 = 4.2 MB
    uint4* kvb8  = qb8 + (size_t)8 * NTOK;                  // 16 * NTOK uint4 = 8.4 MB
    unsigned short* wb = (unsigned short*)(kvb8 + (size_t)16 * NTOK);  // 49152 bf16
    unsigned short* qkv_wb  = wb;
    unsigned short* fc1_wb  = wb + 12288;
    unsigned short* fc2_wb  = wb + 28672;
    unsigned short* proj_wb = wb + 45056;

    k_statsprep<<<448, 256, 0, stream>>>(x, stats, qkv_w, fc1_w, fc2_w, proj_w, wb);
    k_qkv      <<<512, 256, 0, stream>>>(x, stats, gn_w, gn_b, qkv_wb, qkv_b, qb8, kvb8);
    k_fused    <<<1024, 512, 0, stream>>>(qb8, kvb8, rpb, proj_wb, proj_b, x,
                                          ln_w, ln_b, fc1_wb, fc1_b, fc2_wb, fc2_b, out);
}